// Round 6
// baseline (9863.635 us; speedup 1.0000x reference)
//
#include <hip/hip_runtime.h>

// Two-layer tanh RNN, H=32, B=64, T=16384. Latency-bound sequential scan.
//
// Round-6: DPP rotation-ring design. One wave per batch, lanes 32-63 duplicate
// lanes 0-31 so wave_ror:1 is an exact 32-element rotation (boundary lanes
// pull the duplicate copy). Lane r owns row r with ROTATION-PERMUTED weights
// w[s] = W[r][(r -/+ s)&31] (direction probed at runtime), so each rotation
// position needs only reg-reg FMAs: zero readlane/SGPR-hazard stalls, zero
// DS ops in the recurrence. Pass A rotates h0n once feeding TWO streams
// (L1B this step + L0 next step); pass B rotates h1n (L1A next step).
// Output: h1n streamed to ws history (coalesced), second kernel does the
// Wout GEMV; butterfly fallback if ws is too small.

#define T_LEN 16384
#define B_SZ  64

template <int CTRL>
__device__ __forceinline__ float dpp_mov(float v) {
  return __int_as_float(__builtin_amdgcn_update_dpp(
      __float_as_int(v), __float_as_int(v), CTRL, 0xF, 0xF, false));
}
#define ROR1(v) dpp_mov<0x13C>(v)   // wave_ror:1 (direction probed at runtime)

template <int CTRL, int RMASK>
__device__ __forceinline__ float dpp_add(float v) {
  int t = __builtin_amdgcn_update_dpp(0, __float_as_int(v), CTRL, RMASK, 0xf, true);
  return v + __int_as_float(t);
}

__device__ __forceinline__ float rl(float v, int lane) {
  return __int_as_float(__builtin_amdgcn_readlane(__float_as_int(v), lane));
}

__device__ __forceinline__ float tanh_fast(float v) {
  float e = __expf(2.0f * v);
  return 1.0f - __fdividef(2.0f, e + 1.0f);
}

template <bool USE_WS>
__global__ __launch_bounds__(64, 1) void rnn2_kernel(
    const float* __restrict__ x,    const float* __restrict__ hs,
    const float* __restrict__ Wih0, const float* __restrict__ Whh0,
    const float* __restrict__ bih0, const float* __restrict__ bhh0,
    const float* __restrict__ Wih1, const float* __restrict__ Whh1,
    const float* __restrict__ bih1, const float* __restrict__ bhh1,
    const float* __restrict__ Wout, const float* __restrict__ bout,
    float* __restrict__ out, float* __restrict__ hist)
{
  const int m = (int)threadIdx.x;
  const int r = m & 31;
  const int b = (int)blockIdx.x;

  // Probe rotation direction: after ROR1, lane 0 holds 63 (i <- i-1) or 1.
  const bool flip = ((int)rl(ROR1((float)m), 0) == 63);  // true: ring_s[r]=h[(r-s)&31]

  // Rotation-permuted weight rows (96 VGPRs). j(s) matches ring position s.
  float w0[32], wi1[32], wh1[32];
#pragma unroll
  for (int s = 0; s < 32; ++s) {
    int j = (flip ? (r - s) : (r + s)) & 31;
    w0[s]  = Whh0[r * 32 + j];
    wi1[s] = Wih1[r * 32 + j];
    wh1[s] = Whh1[r * 32 + j];
  }
  const float wih0_r = Wih0[r];
  const float bias0  = bih0[r] + bhh0[r];
  const float bias1  = bih1[r] + bhh1[r];
  const float wout_r = Wout[r];
  const float bo     = bout[0];

  float h0 = hs[b * 32 + r];
  float h1 = hs[2048 + b * 32 + r];

  // Initial accumulations: a = Whh0@h0_init, d = Whh1@h1_init (ring passes).
  float a0 = 0.f, a1 = 0.f, d0 = 0.f, d1 = 0.f;
  {
    float ra = h0, rb = h1;
#pragma unroll
    for (int s = 0; s < 32; ++s) {
      if (s & 1) { a1 = fmaf(w0[s], ra, a1); d1 = fmaf(wh1[s], rb, d1); }
      else       { a0 = fmaf(w0[s], ra, a0); d0 = fmaf(wh1[s], rb, d0); }
      if (s < 31) { ra = ROR1(ra); rb = ROR1(rb); }
    }
  }

  const float* xb   = x + (size_t)b * T_LEN;
  float*       outp = out + (size_t)b * T_LEN;       // outs[b*T + t]
  float*       hf   = out + (size_t)B_SZ * T_LEN;    // h_final [2,B,H]

  float xchunk = xb[r];   // lanes 0..31 hold x[t0 + r]
  float obuf   = 0.f;

  for (int t0 = 0; t0 < T_LEN; t0 += 32) {
    int nid = t0 + 32 + r;
    if (nid >= T_LEN) nid = T_LEN - 1;
    float xnext = xb[nid];  // prefetch next window

#pragma unroll 2
    for (int t2 = 0; t2 < 32; ++t2) {
      float xv  = rl(xchunk, t2);
      float h0n = tanh_fast(fmaf(xv, wih0_r, bias0) + (a0 + a1));

      // Pass A: rotate h0n; accumulate L1B (c, this step) + L0 (a, next step).
      float c0 = 0.f, c1 = 0.f;
      a0 = 0.f; a1 = 0.f;
      {
        float ring = h0n;
#pragma unroll
        for (int s = 0; s < 32; ++s) {
          if (s & 1) { c1 = fmaf(wi1[s], ring, c1); a1 = fmaf(w0[s], ring, a1); }
          else       { c0 = fmaf(wi1[s], ring, c0); a0 = fmaf(w0[s], ring, a0); }
          if (s < 31) ring = ROR1(ring);
        }
      }
      float h1n = tanh_fast(bias1 + ((c0 + c1) + (d0 + d1)));

      // Pass B: rotate h1n; accumulate L1A (d, next step).
      d0 = 0.f; d1 = 0.f;
      {
        float ring = h1n;
#pragma unroll
        for (int s = 0; s < 32; ++s) {
          if (s & 1) d1 = fmaf(wh1[s], ring, d1);
          else       d0 = fmaf(wh1[s], ring, d0);
          if (s < 31) ring = ROR1(ring);
        }
      }

      if (USE_WS) {
        // Stream h1n to history [t][b][r] (128 B coalesced from lanes 0-31).
        if (m < 32) hist[(size_t)(t0 + t2) * 2048 + b * 32 + r] = h1n;
      } else {
        // Fallback: in-kernel Wout dot via DPP butterfly (round-5 proven).
        float o = h1n * wout_r;
        o = dpp_add<0x111, 0xf>(o);
        o = dpp_add<0x112, 0xf>(o);
        o = dpp_add<0x114, 0xf>(o);
        o = dpp_add<0x118, 0xf>(o);
        o = dpp_add<0x142, 0xa>(o);
        float so = rl(o, 31);
        obuf = (m == t2) ? so : obuf;
      }

      h0 = h0n;
      h1 = h1n;
    }

    if (!USE_WS) { if (m < 32) outp[t0 + r] = obuf + bo; }
    xchunk = xnext;
  }

  if (m < 32) {
    hf[b * 32 + r]        = h0;
    hf[2048 + b * 32 + r] = h1;
  }
}

// Second kernel: outs[b*T+t] = dot(hist[t][b][:], Wout) + bo. ~134 MB read,
// memory-bound ~35 us. Coalesced out writes; float4 reads.
__global__ __launch_bounds__(256) void out_gemv(
    const float* __restrict__ hist, const float* __restrict__ Wout,
    const float* __restrict__ bout, float* __restrict__ out)
{
  int tid = (int)blockIdx.x * 256 + (int)threadIdx.x;  // = b*T + t
  int t = tid & (T_LEN - 1);
  int b = tid >> 14;
  const float4* hp = (const float4*)(hist + (size_t)t * 2048 + b * 32);
  const float4* wp = (const float4*)Wout;
  float acc = 0.f;
#pragma unroll
  for (int k = 0; k < 8; ++k) {
    float4 h = hp[k], w = wp[k];
    acc += h.x * w.x + h.y * w.y + h.z * w.z + h.w * w.w;
  }
  out[tid] = acc + bout[0];
}

extern "C" void kernel_launch(void* const* d_in, const int* in_sizes, int n_in,
                              void* d_out, int out_size, void* d_ws, size_t ws_size,
                              hipStream_t stream) {
  const size_t need = (size_t)T_LEN * 2048 * sizeof(float);  // 134.2 MB
  if (ws_size >= need) {
    rnn2_kernel<true><<<dim3(B_SZ), dim3(64), 0, stream>>>(
        (const float*)d_in[0],  (const float*)d_in[1],  (const float*)d_in[2],
        (const float*)d_in[3],  (const float*)d_in[4],  (const float*)d_in[5],
        (const float*)d_in[6],  (const float*)d_in[7],  (const float*)d_in[8],
        (const float*)d_in[9],  (const float*)d_in[10], (const float*)d_in[11],
        (float*)d_out, (float*)d_ws);
    out_gemv<<<dim3((B_SZ * T_LEN) / 256), dim3(256), 0, stream>>>(
        (const float*)d_ws, (const float*)d_in[10], (const float*)d_in[11],
        (float*)d_out);
  } else {
    rnn2_kernel<false><<<dim3(B_SZ), dim3(64), 0, stream>>>(
        (const float*)d_in[0],  (const float*)d_in[1],  (const float*)d_in[2],
        (const float*)d_in[3],  (const float*)d_in[4],  (const float*)d_in[5],
        (const float*)d_in[6],  (const float*)d_in[7],  (const float*)d_in[8],
        (const float*)d_in[9],  (const float*)d_in[10], (const float*)d_in[11],
        (float*)d_out, nullptr);
  }
}

// Round 7
// 6812.815 us; speedup vs baseline: 1.4478x; 1.4478x over previous
//
#include <hip/hip_runtime.h>

// Two-layer tanh RNN, H=32, B=64, T=16384. Latency-bound sequential scan.
//
// Round-7: round-5 readlane structure + ONE-STEP SOFTWARE PIPELINING of the
// broadcast. Iteration i computes h0n(i) AND h1n(i-1) (L1 is feed-forward
// from L0, so lagging it one step is legal). All 96 FMAs consume SGPRs
// (sh0 = h0n(i-1), sh1 = h1n(i-2)) written at the END of the PREVIOUS
// iteration -> readlane->SGPR->VALU hazard distance ~ a full step instead of
// a few instructions (round-5's suspected ~250 cyc/step of wait states).
// Round-6's DPP ring is abandoned (serial chain = latency structure, 1440
// cyc/step). Output: h1n streamed to ws history (coalesced 128 B/step/wave),
// round-6-proven out_gemv does the Wout dots; butterfly fallback if no ws.

#define T_LEN 16384
#define B_SZ  64

__device__ __forceinline__ float rl(float v, int lane) {
  return __int_as_float(__builtin_amdgcn_readlane(__float_as_int(v), lane));
}

template <int CTRL, int RMASK>
__device__ __forceinline__ float dpp_add(float v) {
  int t = __builtin_amdgcn_update_dpp(0, __float_as_int(v), CTRL, RMASK, 0xf, true);
  return v + __int_as_float(t);
}

__device__ __forceinline__ float tanh_fast(float v) {
  float e = __expf(2.0f * v);
  return 1.0f - __fdividef(2.0f, e + 1.0f);
}

template <bool USE_WS>
__global__ __launch_bounds__(64, 1) void rnn2_kernel(
    const float* __restrict__ x,    const float* __restrict__ hs,
    const float* __restrict__ Wih0, const float* __restrict__ Whh0,
    const float* __restrict__ bih0, const float* __restrict__ bhh0,
    const float* __restrict__ Wih1, const float* __restrict__ Whh1,
    const float* __restrict__ bih1, const float* __restrict__ bhh1,
    const float* __restrict__ Wout, const float* __restrict__ bout,
    float* __restrict__ out, float* __restrict__ hist)
{
  const int m = (int)threadIdx.x;
  const int r = m & 31;            // row this lane owns (upper half duplicates)
  const int b = (int)blockIdx.x;   // one batch per wave

  // Full weight rows in VGPRs (96 VGPRs).
  float w0[32], wi1[32], wh1[32];
#pragma unroll
  for (int k = 0; k < 8; ++k) {
    float4 q0 = ((const float4*)(Whh0 + r * 32))[k];
    w0[4*k] = q0.x;  w0[4*k+1] = q0.y;  w0[4*k+2] = q0.z;  w0[4*k+3] = q0.w;
    float4 q1 = ((const float4*)(Wih1 + r * 32))[k];
    wi1[4*k] = q1.x; wi1[4*k+1] = q1.y; wi1[4*k+2] = q1.z; wi1[4*k+3] = q1.w;
    float4 q2 = ((const float4*)(Whh1 + r * 32))[k];
    wh1[4*k] = q2.x; wh1[4*k+1] = q2.y; wh1[4*k+2] = q2.z; wh1[4*k+3] = q2.w;
  }
  const float wih0_r = Wih0[r];
  const float bias0  = bih0[r] + bhh0[r];
  const float bias1  = bih1[r] + bhh1[r];
  const float wout_r = Wout[r];
  const float bo     = bout[0];

  const float h0i = hs[b * 32 + r];
  const float h1i = hs[2048 + b * 32 + r];

  // Pipelined broadcast state: sh0 = h0n(i-1), sh1 = h1n(i-2).
  float sh0[32], sh1[32];
#pragma unroll
  for (int j = 0; j < 32; ++j) { sh0[j] = rl(h0i, j); sh1[j] = rl(h1i, j); }

  float h0 = h0i;   // carries h0n(i) for h_final

  const float* xb   = x + (size_t)b * T_LEN;
  float*       outp = out + (size_t)b * T_LEN;       // outs[b*T + t]
  float*       hf   = out + (size_t)B_SZ * T_LEN;    // h_final [2,B,H]

  float xchunk = xb[r];   // lanes 0..31 hold x[t0 + r]

  for (int t0 = 0; t0 < T_LEN; t0 += 32) {
    int nid = t0 + 32 + r;
    if (nid >= T_LEN) nid = T_LEN - 1;
    float xnext = xb[nid];  // prefetch next window (32 steps of slack)

#pragma unroll 2
    for (int t2 = 0; t2 < 32; ++t2) {
      const int t = t0 + t2;
      float xv = rl(xchunk, t2);

      // a = Whh0 @ h0n(t-1)          [sh0: written last iteration]
      float a0 = 0.f, a1 = 0.f, a2 = 0.f, a3 = 0.f;
      // c = bias1 + Wih1 @ h0n(t-1) + Whh1 @ h1n(t-2)   [sh0, sh1: last iter]
      float c0 = bias1, c1 = 0.f, c2 = 0.f, c3 = 0.f;
#pragma unroll
      for (int k = 0; k < 8; ++k) {
        a0 = fmaf(w0[4*k],    sh0[4*k],   a0);
        a1 = fmaf(w0[4*k+1],  sh0[4*k+1], a1);
        a2 = fmaf(w0[4*k+2],  sh0[4*k+2], a2);
        a3 = fmaf(w0[4*k+3],  sh0[4*k+3], a3);
        c0 = fmaf(wi1[4*k],   sh0[4*k],   c0);
        c1 = fmaf(wi1[4*k+1], sh0[4*k+1], c1);
        c2 = fmaf(wi1[4*k+2], sh0[4*k+2], c2);
        c3 = fmaf(wi1[4*k+3], sh0[4*k+3], c3);
        c0 = fmaf(wh1[4*k],   sh1[4*k],   c0);
        c1 = fmaf(wh1[4*k+1], sh1[4*k+1], c1);
        c2 = fmaf(wh1[4*k+2], sh1[4*k+2], c2);
        c3 = fmaf(wh1[4*k+3], sh1[4*k+3], c3);
      }
      float h0n = tanh_fast(fmaf(xv, wih0_r, bias0) + ((a0 + a1) + (a2 + a3)));
      float h1c = tanh_fast((c0 + c1) + (c2 + c3));
      // h1n(t-1); at t==0 the true h1n(-1) is the initial state.
      float h1p = (t == 0) ? h1i : h1c;

      if (USE_WS) {
        // Stream h1n(t-1) to history [t-1][b][r] (128 B coalesced).
        if (m < 32 && t > 0) hist[(size_t)(t - 1) * 2048 + b * 32 + r] = h1p;
      } else {
        float o = h1p * wout_r;
        o = dpp_add<0x111, 0xf>(o);
        o = dpp_add<0x112, 0xf>(o);
        o = dpp_add<0x114, 0xf>(o);
        o = dpp_add<0x118, 0xf>(o);
        o = dpp_add<0x142, 0xa>(o);
        float so = rl(o, 31);
        if (m == 0 && t > 0) outp[t - 1] = so + bo;
      }

      // Broadcast refresh at iteration end: consumed NEXT iteration
      // (~full-step producer->consumer distance, no SGPR-write hazards).
#pragma unroll
      for (int j = 0; j < 32; ++j) sh0[j] = rl(h0n, j);
#pragma unroll
      for (int j = 0; j < 32; ++j) sh1[j] = rl(h1p, j);

      h0 = h0n;
    }
    xchunk = xnext;
  }

  // Epilogue: h1n(T-1) = tanh(bias1 + Wih1@h0n(T-1) + Whh1@h1n(T-2)).
  {
    float c0 = bias1, c1 = 0.f, c2 = 0.f, c3 = 0.f;
#pragma unroll
    for (int k = 0; k < 8; ++k) {
      c0 = fmaf(wi1[4*k],   sh0[4*k],   c0);
      c1 = fmaf(wi1[4*k+1], sh0[4*k+1], c1);
      c2 = fmaf(wi1[4*k+2], sh0[4*k+2], c2);
      c3 = fmaf(wi1[4*k+3], sh0[4*k+3], c3);
      c0 = fmaf(wh1[4*k],   sh1[4*k],   c0);
      c1 = fmaf(wh1[4*k+1], sh1[4*k+1], c1);
      c2 = fmaf(wh1[4*k+2], sh1[4*k+2], c2);
      c3 = fmaf(wh1[4*k+3], sh1[4*k+3], c3);
    }
    float h1last = tanh_fast((c0 + c1) + (c2 + c3));

    if (USE_WS) {
      if (m < 32) hist[(size_t)(T_LEN - 1) * 2048 + b * 32 + r] = h1last;
    } else {
      float o = h1last * wout_r;
      o = dpp_add<0x111, 0xf>(o);
      o = dpp_add<0x112, 0xf>(o);
      o = dpp_add<0x114, 0xf>(o);
      o = dpp_add<0x118, 0xf>(o);
      o = dpp_add<0x142, 0xa>(o);
      float so = rl(o, 31);
      if (m == 0) outp[T_LEN - 1] = so + bo;
    }

    if (m < 32) {
      hf[b * 32 + r]        = h0;       // h0n(T-1)
      hf[2048 + b * 32 + r] = h1last;   // h1n(T-1)
    }
  }
}

// outs[b*T+t] = dot(hist[t][b][:], Wout) + bo. ~134 MB read, memory-bound.
__global__ __launch_bounds__(256) void out_gemv(
    const float* __restrict__ hist, const float* __restrict__ Wout,
    const float* __restrict__ bout, float* __restrict__ out)
{
  int tid = (int)blockIdx.x * 256 + (int)threadIdx.x;  // = b*T + t
  int t = tid & (T_LEN - 1);
  int b = tid >> 14;
  const float4* hp = (const float4*)(hist + (size_t)t * 2048 + b * 32);
  const float4* wp = (const float4*)Wout;
  float acc = 0.f;
#pragma unroll
  for (int k = 0; k < 8; ++k) {
    float4 h = hp[k], w = wp[k];
    acc += h.x * w.x + h.y * w.y + h.z * w.z + h.w * w.w;
  }
  out[tid] = acc + bout[0];
}

extern "C" void kernel_launch(void* const* d_in, const int* in_sizes, int n_in,
                              void* d_out, int out_size, void* d_ws, size_t ws_size,
                              hipStream_t stream) {
  const size_t need = (size_t)T_LEN * 2048 * sizeof(float);  // 134.2 MB
  if (ws_size >= need) {
    rnn2_kernel<true><<<dim3(B_SZ), dim3(64), 0, stream>>>(
        (const float*)d_in[0],  (const float*)d_in[1],  (const float*)d_in[2],
        (const float*)d_in[3],  (const float*)d_in[4],  (const float*)d_in[5],
        (const float*)d_in[6],  (const float*)d_in[7],  (const float*)d_in[8],
        (const float*)d_in[9],  (const float*)d_in[10], (const float*)d_in[11],
        (float*)d_out, (float*)d_ws);
    out_gemv<<<dim3((B_SZ * T_LEN) / 256), dim3(256), 0, stream>>>(
        (const float*)d_ws, (const float*)d_in[10], (const float*)d_in[11],
        (float*)d_out);
  } else {
    rnn2_kernel<false><<<dim3(B_SZ), dim3(64), 0, stream>>>(
        (const float*)d_in[0],  (const float*)d_in[1],  (const float*)d_in[2],
        (const float*)d_in[3],  (const float*)d_in[4],  (const float*)d_in[5],
        (const float*)d_in[6],  (const float*)d_in[7],  (const float*)d_in[8],
        (const float*)d_in[9],  (const float*)d_in[10], (const float*)d_in[11],
        (float*)d_out, nullptr);
  }
}

// Round 8
// 5795.675 us; speedup vs baseline: 1.7019x; 1.1755x over previous
//
#include <hip/hip_runtime.h>

// Two-layer tanh RNN, H=32, B=64, T=16384. Latency-bound sequential scan.
//
// Round-8: COMBINED 64x64 RECURRENCE. With the one-step lag (L1 trails L0),
//   g(t) = [h0n(t); h1n(t-1)]  satisfies  g+ = tanh(bias + M g + x-term),
//   M = [[Whh0, 0],[Wih1, Whh1]]  (64x64).
// One wave per batch; lane m owns row m of M -> 64 FMAs/lane, ALL 64 lanes
// useful (rounds 5-7 duplicated work across halves). The zero block's FMA
// slots on lanes<32 carry Wout instead: those lanes compute out(t-2) =
// Wout . h1n(t-2) + bo for free (no DPP butterfly, no 134MB hist pass).
// Broadcast of g: 1 ds_write + 16 uniform-address ds_read_b128 (HW
// broadcast) -> exactly ONE DS turnaround per step (round 3 died on ~6-8;
// rounds 5-7's 64 readlanes/step ran at ~5cyc/instr). ~110 instr/step vs 195.

#define T_LEN 16384
#define B_SZ  64

__device__ __forceinline__ float rl(float v, int lane) {
  return __int_as_float(__builtin_amdgcn_readlane(__float_as_int(v), lane));
}

__device__ __forceinline__ float tanh_fast(float v) {
  // tanh(x) = 1 - 2/(exp(2x)+1); saturates correctly at +/-inf.
  float e = __expf(2.0f * v);
  return 1.0f - __fdividef(2.0f, e + 1.0f);
}

__global__ __launch_bounds__(64, 1) void rnn2_kernel(
    const float* __restrict__ x,    const float* __restrict__ hs,
    const float* __restrict__ Wih0, const float* __restrict__ Whh0,
    const float* __restrict__ bih0, const float* __restrict__ bhh0,
    const float* __restrict__ Wih1, const float* __restrict__ Whh1,
    const float* __restrict__ bih1, const float* __restrict__ bhh1,
    const float* __restrict__ Wout, const float* __restrict__ bout,
    float* __restrict__ out)
{
  __shared__ __align__(16) float gbuf[64];

  const int  m   = (int)threadIdx.x;
  const int  r   = m & 31;
  const bool low = (m < 32);
  const int  b   = (int)blockIdx.x;

  // Row m of M (64 VGPRs). Lanes<32: [Whh0 row | Wout]; lanes>=32:
  // [Wih1 row | Whh1 row].
  const float* pl = low ? (Whh0 + r * 32) : (Wih1 + r * 32);
  const float* ph = low ? Wout            : (Whh1 + r * 32);
  float wA[64];
#pragma unroll
  for (int k = 0; k < 8; ++k) {
    float4 q = ((const float4*)pl)[k];
    wA[4*k+0] = q.x; wA[4*k+1] = q.y; wA[4*k+2] = q.z; wA[4*k+3] = q.w;
    float4 p = ((const float4*)ph)[k];
    wA[32+4*k+0] = p.x; wA[32+4*k+1] = p.y; wA[32+4*k+2] = p.z; wA[32+4*k+3] = p.w;
  }
  const float xw   = low ? Wih0[r] : 0.f;
  const float bsel = low ? (bih0[r] + bhh0[r]) : (bih1[r] + bhh1[r]);
  const float bo   = bout[0];

  // g(init) = [h0_init; h1_init]
  float g = low ? hs[b * 32 + r] : hs[2048 + b * 32 + r];

  const float* xb   = x + (size_t)b * T_LEN;
  float*       outp = out + (size_t)b * T_LEN;       // outs[b*T + t]
  float*       hf   = out + (size_t)B_SZ * T_LEN;    // h_final [2,B,H]

  const float4* gv = (const float4*)gbuf;

  float xchunk = xb[r];   // window of 32 x-values (same in both halves)

  for (int t0 = 0; t0 < T_LEN; t0 += 32) {
    int nid = t0 + 32 + r;
    if (nid >= T_LEN) nid = T_LEN - 1;
    float xnext = xb[nid];  // prefetch next window

#pragma unroll 2
    for (int t2 = 0; t2 < 32; ++t2) {
      const int i = t0 + t2;
      gbuf[m] = g;                       // 1 ds_write (in-order DS pipe)
      float xv = rl(xchunk, t2);

      float aL0 = 0.f, aL1 = 0.f, aL2 = 0.f, aL3 = 0.f;
      float aH0 = 0.f, aH1 = 0.f, aH2 = 0.f, aH3 = 0.f;
#pragma unroll
      for (int k = 0; k < 8; ++k) {
        float4 u = gv[k];                // j = 4k..4k+3   (g lower half)
        aL0 = fmaf(wA[4*k+0], u.x, aL0);
        aL1 = fmaf(wA[4*k+1], u.y, aL1);
        aL2 = fmaf(wA[4*k+2], u.z, aL2);
        aL3 = fmaf(wA[4*k+3], u.w, aL3);
        float4 v = gv[8+k];              // j = 32+4k..    (g upper half)
        aH0 = fmaf(wA[32+4*k+0], v.x, aH0);
        aH1 = fmaf(wA[32+4*k+1], v.y, aH1);
        aH2 = fmaf(wA[32+4*k+2], v.z, aH2);
        aH3 = fmaf(wA[32+4*k+3], v.w, aH3);
      }
      float accL = (aL0 + aL1) + (aL2 + aL3);
      float accH = (aH0 + aH1) + (aH2 + aH3);

      float outv = accH + bo;                          // lanes<32: out(i-2)
      float pre  = fmaf(xv, xw, bsel) + accL + (low ? 0.f : accH);
      float gn   = tanh_fast(pre);
      if (i == 0) gn = low ? gn : g;     // keep h1_init (upper used stale h0)
      if (m == 0 && i >= 2) outp[i - 2] = outv;
      g = gn;
    }
    xchunk = xnext;
  }

  // Epilogue A: g = [h0n(T-1); h1n(T-2)] -> compute h1n(T-1), emit out(T-2).
  {
    gbuf[m] = g;
    float aL0 = 0.f, aL1 = 0.f, aL2 = 0.f, aL3 = 0.f;
    float aH0 = 0.f, aH1 = 0.f, aH2 = 0.f, aH3 = 0.f;
#pragma unroll
    for (int k = 0; k < 8; ++k) {
      float4 u = gv[k];
      aL0 = fmaf(wA[4*k+0], u.x, aL0);
      aL1 = fmaf(wA[4*k+1], u.y, aL1);
      aL2 = fmaf(wA[4*k+2], u.z, aL2);
      aL3 = fmaf(wA[4*k+3], u.w, aL3);
      float4 v = gv[8+k];
      aH0 = fmaf(wA[32+4*k+0], v.x, aH0);
      aH1 = fmaf(wA[32+4*k+1], v.y, aH1);
      aH2 = fmaf(wA[32+4*k+2], v.z, aH2);
      aH3 = fmaf(wA[32+4*k+3], v.w, aH3);
    }
    float accL = (aL0 + aL1) + (aL2 + aL3);
    float accH = (aH0 + aH1) + (aH2 + aH3);
    if (m == 0) outp[T_LEN - 2] = accH + bo;
    float h1l = tanh_fast(bsel + accL + accH);   // upper lanes: h1n(T-1)
    g = low ? g : h1l;                           // [h0n(T-1); h1n(T-1)]
  }

  // Epilogue B: out(T-1) = Wout . h1n(T-1) + bo (upper-half dot on lanes<32).
  {
    gbuf[m] = g;
    float aH0 = 0.f, aH1 = 0.f, aH2 = 0.f, aH3 = 0.f;
#pragma unroll
    for (int k = 0; k < 8; ++k) {
      float4 v = gv[8+k];
      aH0 = fmaf(wA[32+4*k+0], v.x, aH0);
      aH1 = fmaf(wA[32+4*k+1], v.y, aH1);
      aH2 = fmaf(wA[32+4*k+2], v.z, aH2);
      aH3 = fmaf(wA[32+4*k+3], v.w, aH3);
    }
    if (m == 0) outp[T_LEN - 1] = ((aH0 + aH1) + (aH2 + aH3)) + bo;
  }

  // h_final [2,B,H]: lower lanes hold h0n(T-1), upper hold h1n(T-1).
  if (low) hf[b * 32 + r]        = g;
  else     hf[2048 + b * 32 + r] = g;
}

extern "C" void kernel_launch(void* const* d_in, const int* in_sizes, int n_in,
                              void* d_out, int out_size, void* d_ws, size_t ws_size,
                              hipStream_t stream) {
  rnn2_kernel<<<dim3(B_SZ), dim3(64), 0, stream>>>(
      (const float*)d_in[0],  (const float*)d_in[1],  (const float*)d_in[2],
      (const float*)d_in[3],  (const float*)d_in[4],  (const float*)d_in[5],
      (const float*)d_in[6],  (const float*)d_in[7],  (const float*)d_in[8],
      (const float*)d_in[9],  (const float*)d_in[10], (const float*)d_in[11],
      (float*)d_out);
}

// Round 10
// 3841.780 us; speedup vs baseline: 2.5675x; 1.5086x over previous
//
#include <hip/hip_runtime.h>

// Two-layer tanh RNN, H=32, B=64, T=16384. Latency-bound sequential scan.
//
// Round-10: 2-wave producer/consumer split, rewritten defensively after R9's
// correctness failure. All LDS writes are UNCONDITIONAL ALL-LANE writes
// (round-8's proven pattern; R9 used exec-masked writes). Window math is
// t-indexed with no prologue: wave A's window w covers t in [32w, 32w+32);
// the pre-write broadcast gives h0n(t-1), so upper lanes publish
// u(t-1) = b1 + Wih1 . h0n(t-1) into slot t2 — exactly the range wave B's
// (-1)-shifted window wb=w needs (t' = 32wb-1+t2). Wave A lower: Whh0 rows
// (h0 chain). Wave B lower: Whh1 rows (h1 chain, consumes u); upper: Wout
// (out(t'-1) for free from the same broadcast). One barrier per 32 steps;
// 2-barrier epilogue finishes u(T-1), h1n(T-1), out(T-2), out(T-1).

#define T_LEN 16384
#define B_SZ  64
#define NW    (T_LEN / 32)   // 512 windows

__device__ __forceinline__ float rl(float v, int lane) {
  return __int_as_float(__builtin_amdgcn_readlane(__float_as_int(v), lane));
}

__device__ __forceinline__ float tanh_fast(float v) {
  // tanh(x) = 1 - 2/(exp(2x)+1); saturates correctly at +/-inf.
  float e = __expf(2.0f * v);
  return 1.0f - __fdividef(2.0f, e + 1.0f);
}

__global__ __launch_bounds__(128, 1) void rnn2_kernel(
    const float* __restrict__ x,    const float* __restrict__ hs,
    const float* __restrict__ Wih0, const float* __restrict__ Whh0,
    const float* __restrict__ bih0, const float* __restrict__ bhh0,
    const float* __restrict__ Wih1, const float* __restrict__ Whh1,
    const float* __restrict__ bih1, const float* __restrict__ bhh1,
    const float* __restrict__ Wout, const float* __restrict__ bout,
    float* __restrict__ out)
{
  __shared__ __align__(16) float h0buf[64];      // wave-A private; [0..31] = h0n
  __shared__ __align__(16) float h1buf[64];      // wave-B private; [0..31] = h1n
  __shared__ __align__(16) float uwin[2][2048];  // A->B; slot t2: [t2*64+32+r] = u[r]

  const int  tid = (int)threadIdx.x;
  const int  wv  = tid >> 6;           // 0 = wave A (h0), 1 = wave B (h1)
  const int  m   = tid & 63;
  const int  r   = m & 31;
  const bool up  = (m >= 32);
  const int  b   = (int)blockIdx.x;

  // One 32-float weight row per lane:
  //  A: lower = Whh0 row r, upper = Wih1 row r.  B: lower = Whh1 row r, upper = Wout.
  const float* wrow;
  if (wv == 0) wrow = up ? (Wih1 + r * 32) : (Whh0 + r * 32);
  else         wrow = up ? Wout            : (Whh1 + r * 32);
  float w[32];
#pragma unroll
  for (int k = 0; k < 8; ++k) {
    float4 q = ((const float4*)wrow)[k];
    w[4*k] = q.x; w[4*k+1] = q.y; w[4*k+2] = q.z; w[4*k+3] = q.w;
  }

  float xw = 0.f, bini = 0.f;
  if (wv == 0) {
    if (!up) { xw = Wih0[r]; bini = bih0[r] + bhh0[r]; }  // layer-0 bias
    else     { bini = bih1[r] + bhh1[r]; }                // b1 folded into u
  }
  const float bo = bout[0];

  // Init private broadcasts: all-lane writes, lower 32 meaningful.
  if (wv == 0) h0buf[m] = hs[b * 32 + r];
  else         h1buf[m] = hs[2048 + b * 32 + r];
  __syncthreads();

  const float4* h0v = (const float4*)h0buf;
  const float4* h1v = (const float4*)h1buf;

  const float* xb   = x + (size_t)b * T_LEN;
  float*       outp = out + (size_t)b * T_LEN;       // outs[b*T + t]
  float*       hf   = out + (size_t)B_SZ * T_LEN;    // h_final [2,B,H]

  float h0last = 0.f, h1last = 0.f, obuf = 0.f;

  for (int wdx = 0; wdx <= NW; ++wdx) {
    if (wv == 0) {
      if (wdx < NW) {
        const int tb = 32 * wdx;
        float xchunk = xb[tb + r];            // lanes hold x(tb .. tb+31)
        float* ub = &uwin[wdx & 1][0];
#pragma unroll 4
        for (int t2 = 0; t2 < 32; ++t2) {
          // Pre-write broadcast: h0v = h0n(tb+t2-1).
          float a0 = bini, a1 = 0.f, a2 = 0.f, a3 = 0.f;
#pragma unroll
          for (int k = 0; k < 8; ++k) {
            float4 hv = h0v[k];
            a0 = fmaf(w[4*k],   hv.x, a0);
            a1 = fmaf(w[4*k+1], hv.y, a1);
            a2 = fmaf(w[4*k+2], hv.z, a2);
            a3 = fmaf(w[4*k+3], hv.w, a3);
          }
          float acc = (a0 + a1) + (a2 + a3);  // lower: b0+Whh0.h0; upper: u(t-1)[r]
          ub[t2 * 64 + m] = acc;              // all-lane publish (upper half used)
          float xv  = rl(xchunk, t2);
          float h0n = tanh_fast(fmaf(xv, xw, acc));
          h0buf[m] = h0n;                     // all-lane; [0..31] = h0n(tb+t2)
          h0last = h0n;
        }
      }
    } else {
      if (wdx >= 1) {
        const int wb = wdx - 1;               // steps t = 32*wb-1 .. 32*wb+30
        const float* ub = &uwin[wb & 1][0];
#pragma unroll 4
        for (int t2 = 0; t2 < 32; ++t2) {
          const int t = 32 * wb - 1 + t2;
          float uval = ub[t2 * 64 + 32 + r];  // u(t)[r]
          float a0 = up ? 0.f : uval, a1 = 0.f, a2 = 0.f, a3 = 0.f;
#pragma unroll
          for (int k = 0; k < 8; ++k) {
            float4 hv = h1v[k];               // h1n(t-1)
            a0 = fmaf(w[4*k],   hv.x, a0);
            a1 = fmaf(w[4*k+1], hv.y, a1);
            a2 = fmaf(w[4*k+2], hv.z, a2);
            a3 = fmaf(w[4*k+3], hv.w, a3);
          }
          float acc = (a0 + a1) + (a2 + a3);  // lower: pre-h1(t); upper: out(t-1)-bo
          float h1n = tanh_fast(acc);
          obuf = (m == 32 + t2) ? acc : obuf; // upper lane t2 keeps out(t-1)
          if (t >= 0) {                       // uniform: skips only wb=0,t2=0
            h1buf[m] = h1n;                   // all-lane; [0..31] = h1n(t)
            h1last = h1n;
          }
        }
        const int idx = 32 * wb - 2 + r;      // upper lane r holds out(idx)
        if (up && idx >= 0) outp[idx] = obuf + bo;   // coalesced 32-store
      }
    }
    __syncthreads();   // window handoff (uwin parity swap)
  }

  // Epilogue 1 (wave A): publish u(T-1) from h0n(T-1) into uwin[0] slot 0.
  if (wv == 0) {
    float a0 = bini, a1 = 0.f, a2 = 0.f, a3 = 0.f;
#pragma unroll
    for (int k = 0; k < 8; ++k) {
      float4 hv = h0v[k];                     // h0n(T-1)
      a0 = fmaf(w[4*k],   hv.x, a0);
      a1 = fmaf(w[4*k+1], hv.y, a1);
      a2 = fmaf(w[4*k+2], hv.z, a2);
      a3 = fmaf(w[4*k+3], hv.w, a3);
    }
    uwin[0][m] = (a0 + a1) + (a2 + a3);       // all-lane; [32+r] = u(T-1)[r]
  }
  __syncthreads();

  // Epilogue 2 (wave B): h1n(T-1), out(T-2), out(T-1).
  if (wv == 1) {
    float uT = uwin[0][32 + r];
    float a0 = up ? 0.f : uT, a1 = 0.f, a2 = 0.f, a3 = 0.f;
#pragma unroll
    for (int k = 0; k < 8; ++k) {
      float4 hv = h1v[k];                     // h1n(T-2)
      a0 = fmaf(w[4*k],   hv.x, a0);
      a1 = fmaf(w[4*k+1], hv.y, a1);
      a2 = fmaf(w[4*k+2], hv.z, a2);
      a3 = fmaf(w[4*k+3], hv.w, a3);
    }
    float acc = (a0 + a1) + (a2 + a3);
    if (m == 32) outp[T_LEN - 2] = acc + bo;  // out(T-2) = Wout.h1n(T-2)+bo
    float h1T = tanh_fast(acc);               // lower: h1n(T-1)
    h1buf[m] = h1T;                           // all-lane write
    float c0 = 0.f, c1 = 0.f, c2 = 0.f, c3 = 0.f;
#pragma unroll
    for (int k = 0; k < 8; ++k) {
      float4 hv = h1v[k];                     // h1n(T-1) (same-wave in-order)
      c0 = fmaf(w[4*k],   hv.x, c0);
      c1 = fmaf(w[4*k+1], hv.y, c1);
      c2 = fmaf(w[4*k+2], hv.z, c2);
      c3 = fmaf(w[4*k+3], hv.w, c3);
    }
    if (m == 32) outp[T_LEN - 1] = ((c0 + c1) + (c2 + c3)) + bo;
    if (!up) hf[2048 + b * 32 + r] = h1T;     // h_final layer 1
  } else {
    if (!up) hf[b * 32 + r] = h0last;         // h_final layer 0
  }
}

extern "C" void kernel_launch(void* const* d_in, const int* in_sizes, int n_in,
                              void* d_out, int out_size, void* d_ws, size_t ws_size,
                              hipStream_t stream) {
  rnn2_kernel<<<dim3(B_SZ), dim3(128), 0, stream>>>(
      (const float*)d_in[0],  (const float*)d_in[1],  (const float*)d_in[2],
      (const float*)d_in[3],  (const float*)d_in[4],  (const float*)d_in[5],
      (const float*)d_in[6],  (const float*)d_in[7],  (const float*)d_in[8],
      (const float*)d_in[9],  (const float*)d_in[10], (const float*)d_in[11],
      (float*)d_out);
}